// Round 3
// baseline (459.690 us; speedup 1.0000x reference)
//
#include <hip/hip_runtime.h>
#include <hip/hip_bf16.h>
#include <math.h>

#define D_MODEL 1024
#define DD (1024 * 1024)

typedef unsigned short ushort_t;
using short8 = __attribute__((ext_vector_type(8))) short;   // 8 bf16 (4 VGPRs)
using f32x4  = __attribute__((ext_vector_type(4))) float;   // 4 fp32 acc

#define ACT_NONE 0
#define ACT_SILU 1

__device__ __forceinline__ float bf2f(ushort_t u) {
    return __uint_as_float(((unsigned int)u) << 16);
}
__device__ __forceinline__ ushort_t f2bf(float f) {
    unsigned int x = __float_as_uint(f);
    x += 0x7fffu + ((x >> 16) & 1u);   // round-to-nearest-even
    return (ushort_t)(x >> 16);
}

#define GL2LDS(gp, lp)                                                         \
    __builtin_amdgcn_global_load_lds(                                          \
        (const __attribute__((address_space(1))) void*)(gp),                   \
        (__attribute__((address_space(3))) void*)(lp), 16, 0, 0)

// ---------------------------------------------------------------------------
// bf16 GEMM, m97 structure: 128x128 tile, BK=32, 16x16x32 MFMA,
// 4 waves each owning a 64x64 sub-tile (4x4 acc frags).
// A: M x 1024 bf16 row-major.  Bt: 1024 x 1024 bf16, N-major (Bt[n][k]).
// C: bf16 (OUTF32=0) or fp32 (OUTF32=1), M x 1024 row-major.
// Epilogue: per-wave LDS repack (4KB region each) -> 16B coalesced stores.
// ---------------------------------------------------------------------------
template <int ACT, int OUTF32, int BIASF>
__global__ __launch_bounds__(256) void gemm_bf16(
    const ushort_t* __restrict__ A,
    const ushort_t* __restrict__ Bt,
    const float* __restrict__ bias,
    void* __restrict__ Cv, int M)
{
    constexpr int K = 1024, N = 1024;
    __shared__ ushort_t smem[2 * 128 * 32];   // As | Bs (contiguous 16KB)
    ushort_t* As = smem;
    ushort_t* Bs = smem + 128 * 32;

    const int tid  = threadIdx.x;
    const int lane = tid & 63;
    const int wave = tid >> 6;
    const int quad = lane >> 4;
    const int lr   = lane & 15;
    const int bm   = blockIdx.x;
    const int bn   = blockIdx.y;
    const int wm   = (wave >> 1) * 64;   // wave's m offset in tile
    const int wn   = (wave & 1) * 64;    // wave's n offset in tile

    f32x4 acc[4][4];
#pragma unroll
    for (int i = 0; i < 4; i++)
#pragma unroll
        for (int j = 0; j < 4; j++) acc[i][j] = (f32x4){0.f, 0.f, 0.f, 0.f};

    int ci0 = tid, ci1 = tid + 256;
    int am0 = ci0 >> 2, akc0 = (ci0 & 3) ^ ((am0 >> 1) & 3);
    int am1 = ci1 >> 2, akc1 = (ci1 & 3) ^ ((am1 >> 1) & 3);
    const ushort_t* Ab = A + (size_t)(bm * 128) * K;
    const ushort_t* Bb = Bt + (size_t)(bn * 128) * K;

    for (int k0 = 0; k0 < K; k0 += 32) {
        GL2LDS(Ab + (size_t)am0 * K + k0 + akc0 * 8, As + ci0 * 8);
        GL2LDS(Ab + (size_t)am1 * K + k0 + akc1 * 8, As + ci1 * 8);
        GL2LDS(Bb + (size_t)am0 * K + k0 + akc0 * 8, Bs + ci0 * 8);
        GL2LDS(Bb + (size_t)am1 * K + k0 + akc1 * 8, Bs + ci1 * 8);
        __syncthreads();

        short8 af[4], bfr[4];
#pragma unroll
        for (int t = 0; t < 4; t++) {
            int m = wm + t * 16 + lr;
            af[t] = *(const short8*)(As + m * 32 + ((quad ^ ((m >> 1) & 3)) * 8));
            int n = wn + t * 16 + lr;
            bfr[t] = *(const short8*)(Bs + n * 32 + ((quad ^ ((n >> 1) & 3)) * 8));
        }
#pragma unroll
        for (int mt = 0; mt < 4; mt++)
#pragma unroll
            for (int nt = 0; nt < 4; nt++)
                acc[mt][nt] = __builtin_amdgcn_mfma_f32_16x16x32_bf16(
                    af[mt], bfr[nt], acc[mt][nt], 0, 0, 0);
        __syncthreads();
    }

    // ---- epilogue: bias (+SiLU), per-wave LDS repack, wide stores ----
    float bv[4];
#pragma unroll
    for (int nt = 0; nt < 4; nt++)
        bv[nt] = BIASF ? bias[bn * 128 + wn + nt * 16 + lr] : 0.f;

    float* ep = (float*)smem + wave * 1024;   // 16 rows x 64 cols fp32 (4KB)

#pragma unroll
    for (int mt = 0; mt < 4; mt++) {
        __syncthreads();   // previous chunk's LDS reads (or K-loop) complete
#pragma unroll
        for (int nt = 0; nt < 4; nt++) {
#pragma unroll
            for (int r = 0; r < 4; r++) {
                float v = acc[mt][nt][r] + bv[nt];
                if (ACT == ACT_SILU) v = v / (1.f + __expf(-v));
                // quad-XOR swizzle (16-col granularity) -> <=2-way bank alias
                int col = (nt * 16 + lr) ^ (quad * 16);
                ep[(quad * 4 + r) * 64 + col] = v;
            }
        }
        __syncthreads();
        if (OUTF32) {
#pragma unroll
            for (int su = 0; su < 4; su++) {
                int flat = lane + 64 * su;        // 0..255
                int row  = flat >> 4;             // 0..15
                int cg   = flat & 15;             // 4-col group
                int scol = (cg * 4) ^ (((row >> 2) & 3) * 16);
                float4 v = *(float4*)(ep + row * 64 + scol);
                int rg = bm * 128 + wm + mt * 16 + row;
                int cl = bn * 128 + wn + cg * 4;
                *(float4*)((float*)Cv + (size_t)rg * N + cl) = v;
            }
        } else {
#pragma unroll
            for (int su = 0; su < 2; su++) {
                int flat = lane + 64 * su;        // 0..127
                int row  = flat >> 3;             // 0..15
                int cg   = flat & 7;              // 8-col group
                int scol = (cg * 8) ^ (((row >> 2) & 3) * 16);
                const float* p = ep + row * 64 + scol;
                float4 v0 = *(float4*)p;
                float4 v1 = *(float4*)(p + 4);
                union { ushort_t u[8]; uint4 q; } pk;
                pk.u[0] = f2bf(v0.x); pk.u[1] = f2bf(v0.y);
                pk.u[2] = f2bf(v0.z); pk.u[3] = f2bf(v0.w);
                pk.u[4] = f2bf(v1.x); pk.u[5] = f2bf(v1.y);
                pk.u[6] = f2bf(v1.z); pk.u[7] = f2bf(v1.w);
                int rg = bm * 128 + wm + mt * 16 + row;
                int cl = bn * 128 + wn + cg * 8;
                *(uint4*)((ushort_t*)Cv + (size_t)rg * N + cl) = pk.q;
            }
        }
    }
}

// ---------------------------------------------------------------------------
// In-place LayerNorm over bf16 rows of 1024, fp32 math, eps=1e-5.
// ---------------------------------------------------------------------------
__global__ __launch_bounds__(256) void layernorm_bf16(ushort_t* __restrict__ X)
{
    const int row = blockIdx.x;
    const int tid = threadIdx.x;
    ushort_t* x = X + (size_t)row * D_MODEL + tid * 4;

    uint2 u = *(uint2*)x;
    float a = bf2f(u.x & 0xffff), b = bf2f(u.x >> 16);
    float c = bf2f(u.y & 0xffff), d = bf2f(u.y >> 16);
    float s = a + b + c + d;
    float ss = a * a + b * b + c * c + d * d;

#pragma unroll
    for (int off = 32; off > 0; off >>= 1) {
        s += __shfl_down(s, off);
        ss += __shfl_down(ss, off);
    }
    __shared__ float sbuf[4], ssbuf[4];
    const int wave = tid >> 6;
    if ((tid & 63) == 0) { sbuf[wave] = s; ssbuf[wave] = ss; }
    __syncthreads();
    const float S = sbuf[0] + sbuf[1] + sbuf[2] + sbuf[3];
    const float SS = ssbuf[0] + ssbuf[1] + ssbuf[2] + ssbuf[3];
    const float mu = S * (1.f / D_MODEL);
    const float var = SS * (1.f / D_MODEL) - mu * mu;
    const float r = rsqrtf(var + 1e-5f);

    a = (a - mu) * r; b = (b - mu) * r; c = (c - mu) * r; d = (d - mu) * r;
    u.x = (unsigned)f2bf(a) | ((unsigned)f2bf(b) << 16);
    u.y = (unsigned)f2bf(c) | ((unsigned)f2bf(d) << 16);
    *(uint2*)x = u;
}

// ---------------------------------------------------------------------------
// fp32 -> bf16 bulk convert (8 elems/thread).
// ---------------------------------------------------------------------------
__global__ __launch_bounds__(256) void f32_to_bf16(
    const float* __restrict__ in, ushort_t* __restrict__ out, int n8)
{
    int i = blockIdx.x * 256 + threadIdx.x;
    if (i >= n8) return;
    const float4* p = (const float4*)(in + (size_t)i * 8);
    float4 v0 = p[0], v1 = p[1];
    union { ushort_t u[8]; uint4 v; } pk;
    pk.u[0] = f2bf(v0.x); pk.u[1] = f2bf(v0.y);
    pk.u[2] = f2bf(v0.z); pk.u[3] = f2bf(v0.w);
    pk.u[4] = f2bf(v1.x); pk.u[5] = f2bf(v1.y);
    pk.u[6] = f2bf(v1.z); pk.u[7] = f2bf(v1.w);
    *(uint4*)(out + (size_t)i * 8) = pk.v;
}

// ---------------------------------------------------------------------------
// Transpose + convert weight matrices (1024x1024 fp32 K-major) -> bf16 N-major.
// z: 0=wq, 1..3=mlp_w[0..2], 4=w_out.
// ---------------------------------------------------------------------------
__global__ __launch_bounds__(256) void transpose_convert_w(
    const float* __restrict__ wq, const float* __restrict__ mlp_w,
    const float* __restrict__ w_out, ushort_t* __restrict__ out)
{
    const int z = blockIdx.z;
    const float* src = (z == 0) ? wq : (z < 4) ? (mlp_w + (size_t)(z - 1) * DD) : w_out;
    ushort_t* dst = out + (size_t)z * DD;

    __shared__ float tile[32][33];
    const int r = threadIdx.x >> 5;    // 0..7
    const int c = threadIdx.x & 31;    // 0..31
    const int k0 = blockIdx.x * 32;
    const int n0 = blockIdx.y * 32;

#pragma unroll
    for (int i = 0; i < 4; i++)
        tile[r + 8 * i][c] = src[(size_t)(k0 + r + 8 * i) * D_MODEL + n0 + c];
    __syncthreads();
#pragma unroll
    for (int i = 0; i < 4; i++)
        dst[(size_t)(n0 + r + 8 * i) * D_MODEL + k0 + c] = f2bf(tile[c][r + 8 * i]);
}

// ---------------------------------------------------------------------------
// bf[n] = sum_k b3[k] * Wout[k][n] + bout[n]   (fp32, 1024 threads)
// ---------------------------------------------------------------------------
__global__ __launch_bounds__(256) void bias_compose(
    const float* __restrict__ b3, const float* __restrict__ w_out,
    const float* __restrict__ bout, float* __restrict__ bf)
{
    int n = blockIdx.x * 256 + threadIdx.x;
    float s = 0.f;
    for (int k = 0; k < D_MODEL; k++)
        s = fmaf(b3[k], w_out[(size_t)k * D_MODEL + n], s);
    bf[n] = s + bout[n];
}

// ---------------------------------------------------------------------------
extern "C" void kernel_launch(void* const* d_in, const int* in_sizes, int n_in,
                              void* d_out, int out_size, void* d_ws, size_t ws_size,
                              hipStream_t stream)
{
    const float* x     = (const float*)d_in[0];
    const float* wq    = (const float*)d_in[1];
    const float* bq    = (const float*)d_in[2];
    const float* mlp_w = (const float*)d_in[3];
    const float* mlp_b = (const float*)d_in[4];
    const float* w_out = (const float*)d_in[5];
    const float* b_out = (const float*)d_in[6];

    const int D = D_MODEL;
    const int M = in_sizes[0] / D;   // 16384

    // ws layout (ushort units): wt[0..5)=transposed weights (10MB) | w3b (2MB)
    // | wtF (2MB) | Q (32MB) | bf (4KB)
    ushort_t* wt  = (ushort_t*)d_ws;
    ushort_t* w3b = wt + (size_t)5 * DD;
    ushort_t* wtF = wt + (size_t)6 * DD;
    ushort_t* Q   = wt + (size_t)7 * DD;
    float*    bf  = (float*)(Q + (size_t)M * D);
    ushort_t* P   = (ushort_t*)d_out;   // bf16 acts alias d_out's 64MB fp32

    // 1. transposed bf16 weights: wq, mlp0..2, w_out
    transpose_convert_w<<<dim3(32, 32, 5), 256, 0, stream>>>(wq, mlp_w, w_out, wt);
    // 2. W3 -> bf16 (plain layout)
    f32_to_bf16<<<(DD / 8 + 255) / 256, 256, 0, stream>>>(mlp_w + (size_t)3 * DD, w3b, DD / 8);
    // 3. Wf^T = Wout^T @ W3^T  (N-major rep of Wf = W3*Wout)
    gemm_bf16<ACT_NONE, 0, 0><<<dim3(8, 8), 256, 0, stream>>>(wt + (size_t)4 * DD, w3b, nullptr, wtF, 1024);
    // 4. bf = b3 @ Wout + bout
    bias_compose<<<4, 256, 0, stream>>>(mlp_b + 3 * D, w_out, b_out, bf);
    // 5. x -> bf16 into Q
    f32_to_bf16<<<(M * D / 8 + 255) / 256, 256, 0, stream>>>(x, Q, M * D / 8);

    dim3 grid(M / 128, D / 128);
    // 6. q = x @ wq + bq -> P
    gemm_bf16<ACT_NONE, 0, 1><<<grid, 256, 0, stream>>>(Q, wt + (size_t)0 * DD, bq, P, M);
    // 7. LN in place on P
    layernorm_bf16<<<M, 256, 0, stream>>>(P);
    // 8-10. MLP layers 0..2 with SiLU
    gemm_bf16<ACT_SILU, 0, 1><<<grid, 256, 0, stream>>>(P, wt + (size_t)1 * DD, mlp_b + 0 * D, Q, M);
    gemm_bf16<ACT_SILU, 0, 1><<<grid, 256, 0, stream>>>(Q, wt + (size_t)2 * DD, mlp_b + 1 * D, P, M);
    gemm_bf16<ACT_SILU, 0, 1><<<grid, 256, 0, stream>>>(P, wt + (size_t)3 * DD, mlp_b + 2 * D, Q, M);
    // 11. fused (layer3 + out proj): out = h3 @ Wf + bf -> d_out fp32
    //     reads Q (ws) so no alias hazard with d_out.
    gemm_bf16<ACT_NONE, 1, 1><<<grid, 256, 0, stream>>>(Q, wtF, bf, d_out, M);
}